// Round 1
// baseline (312.063 us; speedup 1.0000x reference)
//
#include <hip/hip_runtime.h>
#include <math.h>

#define LOG2E 1.4426950408889634f

// e^-1 .. e^-9
#define E1 0.36787944117144233f
#define E2 0.1353352832366127f
#define E3 0.049787068367863944f
#define E4 0.018315638888734179f
#define E5 0.006737946999085467f
#define E6 0.0024787521766663585f
#define E7 0.0009118819655545162f
#define E8 0.00033546262790251185f
#define E9 0.00012340980408667956f

__device__ __forceinline__ float fexp2(float x) { return __builtin_amdgcn_exp2f(x); }
__device__ __forceinline__ float frsq(float x)  { return __builtin_amdgcn_rsqf(x); }

// One block per batch element. 256 threads = 4 waves.
// Thread owns q-row (tid&31) in registers; documents tiled 64-wide through LDS.
__global__ __launch_bounds__(256, 2) void knrm_kernel(
    const int* __restrict__ q1, const int* __restrict__ d1,
    const int* __restrict__ q2, const int* __restrict__ d2,
    const float* __restrict__ emb, const float* __restrict__ mlp_w,
    const float* __restrict__ mlp_b, float* __restrict__ out)
{
    __shared__ float qv[32][52];     // padded rows (52*4 = 208B, 16B aligned)
    __shared__ float dv[64][52];
    __shared__ float rnq[32];
    __shared__ float rnd[64];
    __shared__ float Swk[4][21][32]; // per-wave partial S[q][k]
    __shared__ float wred[4];

    const int tid  = threadIdx.x;
    const int b    = blockIdx.x;
    const int lane = tid & 63;
    const int wave = tid >> 6;
    const int myq  = tid & 31;
    const int row  = tid >> 5;       // 0..7 : which d-phase this thread covers

    float logitA = 0.f, logitB = 0.f;

    for (int pass = 0; pass < 2; ++pass) {
        const int* qidx = (pass == 0 ? q1 : q2) + b * 32;
        const int* didx = (pass == 0 ? d1 : d2) + b * 512;

        // ---- stage q tile (32 rows x 50 floats) as float2 ----
        __syncthreads();  // protect qv overwrite / prior-pass LDS reads
        for (int i = tid; i < 32 * 25; i += 256) {
            int t  = (i * 5243) >> 17;   // i / 25
            int e2 = i - t * 25;
            ((float2*)&qv[t][0])[e2] =
                ((const float2*)(emb + (size_t)qidx[t] * 50))[e2];
        }
        __syncthreads();
        if (tid < 32) {
            float s = 0.f;
            #pragma unroll
            for (int e = 0; e < 50; ++e) { float v = qv[tid][e]; s = fmaf(v, v, s); }
            rnq[tid] = frsq(s);
        }
        __syncthreads();

        // ---- my q row -> registers, pre-scaled by 1/||q|| ----
        float4 q4[12]; float2 qt;
        {
            const float4* qp = (const float4*)&qv[myq][0];
            float rq = rnq[myq];
            #pragma unroll
            for (int i = 0; i < 12; ++i) {
                float4 v = qp[i];
                v.x *= rq; v.y *= rq; v.z *= rq; v.w *= rq;
                q4[i] = v;
            }
            qt.x = qv[myq][48] * rq;
            qt.y = qv[myq][49] * rq;
        }

        float acc[21];
        #pragma unroll
        for (int k = 0; k < 21; ++k) acc[k] = 0.f;

        // ---- document tiles: 8 chunks of 64 ----
        for (int c = 0; c < 8; ++c) {
            __syncthreads();  // previous chunk compute done before overwrite
            for (int i = tid; i < 64 * 25; i += 256) {
                int t  = (i * 5243) >> 17;   // i / 25
                int e2 = i - t * 25;
                ((float2*)&dv[t][0])[e2] =
                    ((const float2*)(emb + (size_t)didx[c * 64 + t] * 50))[e2];
            }
            __syncthreads();
            if (tid < 64) {
                float s = 0.f;
                #pragma unroll
                for (int e = 0; e < 50; ++e) { float v = dv[tid][e]; s = fmaf(v, v, s); }
                rnd[tid] = frsq(s);
            }
            __syncthreads();

            #pragma unroll 4
            for (int j = 0; j < 8; ++j) {
                const int loc = row + 8 * j;
                const float4* dp = (const float4*)&dv[loc][0];
                float s0 = 0.f, s1 = 0.f, s2 = 0.f, s3 = 0.f;
                #pragma unroll
                for (int i = 0; i < 12; ++i) {
                    float4 d4 = dp[i];
                    s0 = fmaf(q4[i].x, d4.x, s0);
                    s1 = fmaf(q4[i].y, d4.y, s1);
                    s2 = fmaf(q4[i].z, d4.z, s2);
                    s3 = fmaf(q4[i].w, d4.w, s3);
                }
                float2 dt = *(const float2*)&dv[loc][48];
                s0 = fmaf(qt.x, dt.x, s0);
                s1 = fmaf(qt.y, dt.y, s1);
                float s = ((s0 + s1) + (s2 + s3)) * rnd[loc];

                // 21 Gaussian kernels via multiplicative recurrence.
                // g_k = exp(-50 (s-mu_k)^2), mu_k = -0.95 + 0.1k (k=0..19)
                // g_{k+1} = g_k * e^{10 s} * e^{9-k}
                float r  = fexp2( 14.426950408889634f * s);   // e^{10 s}
                float ri = fexp2(-14.426950408889634f * s);   // e^{-10 s}
                float t9 = s + 0.05f;                         // center at mu_9
                float g  = fexp2(-72.13475204444817f * (t9 * t9));
                acc[9] += g;
                float gu = g;
                gu *= r;       acc[10] += gu;
                gu *= r * E1;  acc[11] += gu;
                gu *= r * E2;  acc[12] += gu;
                gu *= r * E3;  acc[13] += gu;
                gu *= r * E4;  acc[14] += gu;
                gu *= r * E5;  acc[15] += gu;
                gu *= r * E6;  acc[16] += gu;
                gu *= r * E7;  acc[17] += gu;
                gu *= r * E8;  acc[18] += gu;
                gu *= r * E9;  acc[19] += gu;
                float gd = g;
                gd *= ri * E1; acc[8] += gd;
                gd *= ri * E2; acc[7] += gd;
                gd *= ri * E3; acc[6] += gd;
                gd *= ri * E4; acc[5] += gd;
                gd *= ri * E5; acc[4] += gd;
                gd *= ri * E6; acc[3] += gd;
                gd *= ri * E7; acc[2] += gd;
                gd *= ri * E8; acc[1] += gd;
                gd *= ri * E9; acc[0] += gd;
                // exact kernel: mu=1, sigma=0.001 -> exp(-5e5 (s-1)^2)
                float te = s - 1.0f;
                acc[20] += fexp2(-721347.5204444817f * (te * te));
            }
        }

        // ---- reduce the 8 threads sharing each q ----
        #pragma unroll
        for (int k = 0; k < 21; ++k) acc[k] += __shfl_xor(acc[k], 32, 64);
        if (lane < 32) {
            #pragma unroll
            for (int k = 0; k < 21; ++k) Swk[wave][k][lane] = acc[k];
        }
        __syncthreads();

        // ---- log1p + kernel weights + block reduction ----
        float local = 0.f;
        for (int p = tid; p < 21 * 32; p += 256) {
            int k = p >> 5, q = p & 31;
            float v = Swk[0][k][q] + Swk[1][k][q] + Swk[2][k][q] + Swk[3][k][q];
            local += mlp_w[k] * log1pf(v);
        }
        #pragma unroll
        for (int off = 1; off < 64; off <<= 1) local += __shfl_xor(local, off, 64);
        if (lane == 0) wred[wave] = local;
        __syncthreads();
        if (tid == 0) {
            float l = wred[0] + wred[1] + wred[2] + wred[3] + mlp_b[0];
            if (pass == 0) logitA = l; else logitB = l;
        }
    }

    if (tid == 0) {
        float x = logitA - logitB;          // mlp_b cancels but kept for exactness
        out[b] = 1.0f / (1.0f + fexp2(-LOG2E * x));
    }
}

extern "C" void kernel_launch(void* const* d_in, const int* in_sizes, int n_in,
                              void* d_out, int out_size, void* d_ws, size_t ws_size,
                              hipStream_t stream) {
    const int*   q1    = (const int*)d_in[0];
    const int*   d1    = (const int*)d_in[1];
    const int*   q2    = (const int*)d_in[2];
    const int*   d2    = (const int*)d_in[3];
    const float* emb   = (const float*)d_in[4];
    const float* mlp_w = (const float*)d_in[5];
    const float* mlp_b = (const float*)d_in[6];
    float*       out   = (float*)d_out;

    const int B = out_size;  // 1024
    knrm_kernel<<<dim3(B), dim3(256), 0, stream>>>(q1, d1, q2, d2, emb, mlp_w, mlp_b, out);
}

// Round 2
// 114.528 us; speedup vs baseline: 2.7248x; 2.7248x over previous
//
#include <hip/hip_runtime.h>
#include <math.h>

#define LOG2E 1.4426950408889634f

// e^-1 .. e^-9 (Gaussian-chain step constants, validated in R1)
#define E1 0.36787944117144233f
#define E2 0.1353352832366127f
#define E3 0.049787068367863944f
#define E4 0.018315638888734179f
#define E5 0.006737946999085467f
#define E6 0.0024787521766663585f
#define E7 0.0009118819655545162f
#define E8 0.00033546262790251185f
#define E9 0.00012340980408667956f

typedef __attribute__((ext_vector_type(8))) short short8;   // 8 bf16 (4 VGPR)
typedef __attribute__((ext_vector_type(4))) float f32x4;    // MFMA C/D

__device__ __forceinline__ float fexp2(float x) { return __builtin_amdgcn_exp2f(x); }

// Stage one (row, 8-element chunk) of a token embedding into hi/lo bf16 LDS
// matrices, pre-scaled by 1/||row||. 8 consecutive lanes cooperate per row.
// LDS chunk position is XOR-swizzled (cb ^ (row&7)) to kill ds_read_b128
// bank conflicts on the MFMA operand loads (T2 pattern).
__device__ __forceinline__ void stage_row_chunk(
    const float* __restrict__ emb, int tok, int row, int cb,
    uint4* __restrict__ hmat, uint4* __restrict__ lmat)
{
    const float* src = emb + (size_t)tok * 50;
    float v[8];
    float ss = 0.f;
    #pragma unroll
    for (int p = 0; p < 4; ++p) {
        int e = cb * 8 + 2 * p;
        float2 t;
        if (e + 2 <= 50) t = *(const float2*)(src + e);
        else             t = make_float2(0.f, 0.f);
        v[2*p]   = t.x;
        v[2*p+1] = t.y;
        ss = fmaf(t.x, t.x, fmaf(t.y, t.y, ss));
    }
    // row-norm over the 8 staging lanes (all lanes get the total)
    ss += __shfl_xor(ss, 1, 64);
    ss += __shfl_xor(ss, 2, 64);
    ss += __shfl_xor(ss, 4, 64);
    float rn = __builtin_amdgcn_rsqf(ss);

    unsigned hw[4], lw[4];
    #pragma unroll
    for (int p = 0; p < 4; ++p) {
        float a = v[2*p]   * rn;
        float b = v[2*p+1] * rn;
        unsigned ba = __float_as_uint(a);
        unsigned bb = __float_as_uint(b);
        unsigned ha = ba & 0xFFFF0000u;
        unsigned hb = bb & 0xFFFF0000u;
        float la = a - __uint_as_float(ha);   // exact residual
        float lb = b - __uint_as_float(hb);
        hw[p] = (ha >> 16) | hb;
        lw[p] = (__float_as_uint(la) >> 16) | (__float_as_uint(lb) & 0xFFFF0000u);
    }
    int cidx = cb ^ (row & 7);
    hmat[row * 8 + cidx] = make_uint4(hw[0], hw[1], hw[2], hw[3]);
    lmat[row * 8 + cidx] = make_uint4(lw[0], lw[1], lw[2], lw[3]);
}

__device__ __forceinline__ short8 frag_ld(const uint4* mat, int row, int chunk)
{
    return __builtin_bit_cast(short8, mat[row * 8 + (chunk ^ (row & 7))]);
}

// One block = one (batch, pass). 256 threads = 4 waves.
// Q (32x50) pre-normalized + bf16-split in LDS; docs in 16 chunks of 32 rows.
// Wave w computes the 16x16 sim tile (qtile = w>>1, dtile = w&1) per chunk
// via 6 MFMAs (hh,hl,lh over K=64), then evaluates 21 Gaussian kernels on its
// 4 f32 sims/lane, accumulating acc[21] per lane (one q-column per lane).
__global__ __launch_bounds__(256, 4) void knrm_pass_kernel(
    const int* __restrict__ q1, const int* __restrict__ d1,
    const int* __restrict__ q2, const int* __restrict__ d2,
    const float* __restrict__ emb, const float* __restrict__ mlp_w,
    float* __restrict__ ws_logit)
{
    __shared__ uint4 qh4[32 * 8], ql4[32 * 8];   // 32 rows x 64 bf16 (hi/lo)
    __shared__ uint4 dh4[32 * 8], dl4[32 * 8];
    __shared__ float Swk[4][21][16];
    __shared__ float wred[4];

    const int tid  = threadIdx.x;
    const int bx   = blockIdx.x;
    const int b    = bx >> 1;
    const int lane = tid & 63;
    const int wave = tid >> 6;
    const int g    = lane >> 4;          // k-group 0..3

    const int* qidx = ((bx & 1) ? q2 : q1) + b * 32;
    const int* didx = ((bx & 1) ? d2 : d1) + b * 512;

    // ---- stage Q (once) ----
    {
        int row = tid >> 3, cb = tid & 7;
        stage_row_chunk(emb, qidx[row], row, cb, qh4, ql4);
    }
    __syncthreads();

    // ---- B-operand fragments (fixed for the whole pass) ----
    const int qt = wave >> 1;
    const int qrow = qt * 16 + (lane & 15);
    short8 Bh0 = frag_ld(qh4, qrow, g);
    short8 Bh1 = frag_ld(qh4, qrow, 4 + g);
    short8 Bl0 = frag_ld(ql4, qrow, g);
    short8 Bl1 = frag_ld(ql4, qrow, 4 + g);

    float acc[21];
    #pragma unroll
    for (int k = 0; k < 21; ++k) acc[k] = 0.f;

    const int dt = wave & 1;

    for (int c = 0; c < 16; ++c) {
        __syncthreads();   // previous chunk fully consumed
        {
            int row = tid >> 3, cb = tid & 7;
            stage_row_chunk(emb, didx[c * 32 + row], row, cb, dh4, dl4);
        }
        __syncthreads();

        int arow = dt * 16 + (lane & 15);
        short8 Ah0 = frag_ld(dh4, arow, g);
        short8 Ah1 = frag_ld(dh4, arow, 4 + g);
        short8 Al0 = frag_ld(dl4, arow, g);
        short8 Al1 = frag_ld(dl4, arow, 4 + g);

        f32x4 C = {0.f, 0.f, 0.f, 0.f};
        C = __builtin_amdgcn_mfma_f32_16x16x32_bf16(Ah0, Bh0, C, 0, 0, 0);
        C = __builtin_amdgcn_mfma_f32_16x16x32_bf16(Ah1, Bh1, C, 0, 0, 0);
        C = __builtin_amdgcn_mfma_f32_16x16x32_bf16(Ah0, Bl0, C, 0, 0, 0);
        C = __builtin_amdgcn_mfma_f32_16x16x32_bf16(Ah1, Bl1, C, 0, 0, 0);
        C = __builtin_amdgcn_mfma_f32_16x16x32_bf16(Al0, Bh0, C, 0, 0, 0);
        C = __builtin_amdgcn_mfma_f32_16x16x32_bf16(Al1, Bh1, C, 0, 0, 0);

        #pragma unroll
        for (int j = 0; j < 4; ++j) {
            float s = C[j];   // already normalized (pre-scaled embeddings)

            float r  = fexp2( 14.426950408889634f * s);   // e^{10 s}
            float ri = fexp2(-14.426950408889634f * s);   // e^{-10 s}
            float t9 = s + 0.05f;                         // center mu_9 = -0.05
            float gc = fexp2(-72.13475204444817f * (t9 * t9));
            acc[9] += gc;
            float gu = gc;
            gu *= r;       acc[10] += gu;
            gu *= r * E1;  acc[11] += gu;
            gu *= r * E2;  acc[12] += gu;
            gu *= r * E3;  acc[13] += gu;
            gu *= r * E4;  acc[14] += gu;
            gu *= r * E5;  acc[15] += gu;
            gu *= r * E6;  acc[16] += gu;
            gu *= r * E7;  acc[17] += gu;
            gu *= r * E8;  acc[18] += gu;
            gu *= r * E9;  acc[19] += gu;
            float gd = gc;
            gd *= ri * E1; acc[8] += gd;
            gd *= ri * E2; acc[7] += gd;
            gd *= ri * E3; acc[6] += gd;
            gd *= ri * E4; acc[5] += gd;
            gd *= ri * E5; acc[4] += gd;
            gd *= ri * E6; acc[3] += gd;
            gd *= ri * E7; acc[2] += gd;
            gd *= ri * E8; acc[1] += gd;
            gd *= ri * E9; acc[0] += gd;
            float te = s - 1.0f;                          // exact kernel
            acc[20] += fexp2(-721347.5204444817f * (te * te));
        }
    }

    // ---- fold the 4 doc-row groups (lanes l, l+16, l+32, l+48 share a q) ----
    #pragma unroll
    for (int k = 0; k < 21; ++k) {
        acc[k] += __shfl_xor(acc[k], 16, 64);
        acc[k] += __shfl_xor(acc[k], 32, 64);
    }
    if (lane < 16) {
        #pragma unroll
        for (int k = 0; k < 21; ++k) Swk[wave][k][lane] = acc[k];
    }
    __syncthreads();

    // ---- log1p + kernel weights + block reduction ----
    float local = 0.f;
    for (int p = tid; p < 21 * 32; p += 256) {
        int k = p >> 5, q = p & 31;
        int wp = (q >> 4) * 2;     // waves {0,1} -> q 0..15, {2,3} -> q 16..31
        float S = Swk[wp][k][q & 15] + Swk[wp + 1][k][q & 15];
        local += mlp_w[k] * log1pf(S);
    }
    #pragma unroll
    for (int off = 1; off < 64; off <<= 1) local += __shfl_xor(local, off, 64);
    if (lane == 0) wred[wave] = local;
    __syncthreads();
    if (tid == 0)
        ws_logit[bx] = wred[0] + wred[1] + wred[2] + wred[3];  // bias cancels in l1-l2
}

__global__ void knrm_final_kernel(const float* __restrict__ ws_logit,
                                  float* __restrict__ out, int B)
{
    int i = blockIdx.x * 256 + threadIdx.x;
    if (i < B) {
        float x = ws_logit[2 * i] - ws_logit[2 * i + 1];
        out[i] = 1.0f / (1.0f + fexp2(-LOG2E * x));
    }
}

extern "C" void kernel_launch(void* const* d_in, const int* in_sizes, int n_in,
                              void* d_out, int out_size, void* d_ws, size_t ws_size,
                              hipStream_t stream) {
    const int*   q1    = (const int*)d_in[0];
    const int*   d1    = (const int*)d_in[1];
    const int*   q2    = (const int*)d_in[2];
    const int*   d2    = (const int*)d_in[3];
    const float* emb   = (const float*)d_in[4];
    const float* mlp_w = (const float*)d_in[5];
    float*       out   = (float*)d_out;
    float*       ws    = (float*)d_ws;     // 2*B floats of logits

    const int B = out_size;  // 1024
    knrm_pass_kernel<<<dim3(2 * B), dim3(256), 0, stream>>>(q1, d1, q2, d2, emb, mlp_w, ws);
    knrm_final_kernel<<<dim3((B + 255) / 256), dim3(256), 0, stream>>>(ws, out, B);
}

// Round 4
// 81.749 us; speedup vs baseline: 3.8173x; 1.4010x over previous
//
#include <hip/hip_runtime.h>
#include <math.h>

#define LOG2E 1.4426950408889634f
#define E1 0.36787944117144233f

typedef __attribute__((ext_vector_type(8))) short short8;   // 8 bf16 (4 VGPR)
typedef __attribute__((ext_vector_type(4))) float f32x4;    // MFMA C/D
typedef __attribute__((ext_vector_type(2))) float f32x2;    // packed-f32 pair

__device__ __forceinline__ float fexp2(float x) { return __builtin_amdgcn_exp2f(x); }

// 21 Gaussian kernels for 2 sims at once, accumulated into acc[21] (f32x2).
// g_k = exp(-50(s-mu_k)^2), mu_k=(2k-19)/20; ratio(k->k+1) = r*e^{9-k}, r=e^{10s}.
// Chain rooted at center k=9 so all intermediates <= 1 (validated R1/R2).
// Native ext-vector ops (NOT inline asm) — backend may select v_pk_*_f32;
// correctness does not depend on it.
__device__ __forceinline__ void kern21(f32x2 s, f32x2* acc)
{
    // NaN insurance: legit sims are in [-1-eps, 1+eps]; clamp keeps the
    // chain overflow-free (r <= e^11, gc >= e^-74) even on bad data.
    s.x = fminf(fmaxf(s.x, -1.1f), 1.1f);
    s.y = fminf(fmaxf(s.y, -1.1f), 1.1f);

    f32x2 m = s * 14.426950408889634f;               // 10*log2(e)*s
    f32x2 r, ri, gc;
    r.x  = fexp2(m.x);   r.y  = fexp2(m.y);          // e^{10 s}
    ri.x = fexp2(-m.x);  ri.y = fexp2(-m.y);         // e^{-10 s}
    f32x2 t9 = s + 0.05f;                            // center mu_9 = -0.05
    f32x2 ga = (t9 * t9) * -72.13475204444817f;      // -50/ln2
    gc.x = fexp2(ga.x);  gc.y = fexp2(ga.y);         // g_9

    acc[9] += gc;
    // up: step(9->10)=r, then *E1 each further step
    f32x2 t = r;
    f32x2 g = gc * t;
    acc[10] += g;
    #pragma unroll
    for (int k = 11; k <= 19; ++k) { t *= E1; g *= t; acc[k] += g; }
    // down: step(9->8)=ri*E1, then *E1 each further step
    t = ri * E1;
    g = gc * t;
    acc[8] += g;
    #pragma unroll
    for (int k = 7; k >= 0; --k) { t *= E1; g *= t; acc[k] += g; }
    // exact kernel (mu=1, sigma=0.001): nonzero only for |s-1| <~ 0.005 ->
    // wave-uniform skip, taken ~0.1% of the time on random vocab.
    if (__any(fmaxf(s.x, s.y) > 0.995f)) {
        f32x2 te = s - 1.0f;
        f32x2 ea = (te * te) * -721347.5204444817f;
        f32x2 ge; ge.x = fexp2(ea.x); ge.y = fexp2(ea.y);
        acc[20] += ge;
    }
}

// ---- fallback in-kernel staging (R2-proven path, used when ws too small) ----
__device__ __forceinline__ void stage_row_chunk(
    const float* __restrict__ emb, int tok, int row, int cb,
    uint4* __restrict__ hmat, uint4* __restrict__ lmat)
{
    const float* src = emb + (size_t)tok * 50;
    float v[8];
    float ss = 0.f;
    #pragma unroll
    for (int p = 0; p < 4; ++p) {
        int e = cb * 8 + 2 * p;
        float2 t;
        if (e + 2 <= 50) t = *(const float2*)(src + e);
        else             t = make_float2(0.f, 0.f);
        v[2*p]   = t.x;
        v[2*p+1] = t.y;
        ss = fmaf(t.x, t.x, fmaf(t.y, t.y, ss));
    }
    ss += __shfl_xor(ss, 1, 64);
    ss += __shfl_xor(ss, 2, 64);
    ss += __shfl_xor(ss, 4, 64);
    float rn = __builtin_amdgcn_rsqf(ss);

    unsigned hw[4], lw[4];
    #pragma unroll
    for (int p = 0; p < 4; ++p) {
        float a = v[2*p]   * rn;
        float b = v[2*p+1] * rn;
        unsigned ha = __float_as_uint(a) & 0xFFFF0000u;
        unsigned hb = __float_as_uint(b) & 0xFFFF0000u;
        float la = a - __uint_as_float(ha);
        float lb = b - __uint_as_float(hb);
        hw[p] = (ha >> 16) | hb;
        lw[p] = (__float_as_uint(la) >> 16) | (__float_as_uint(lb) & 0xFFFF0000u);
    }
    int cidx = cb ^ (row & 7);
    hmat[row * 8 + cidx] = make_uint4(hw[0], hw[1], hw[2], hw[3]);
    lmat[row * 8 + cidx] = make_uint4(lw[0], lw[1], lw[2], lw[3]);
}

// ---- prep: normalize + bf16 hi/lo split every vocab row into ws ----
// layout: wse[tok*16 + 0..7] = hi chunks, wse[tok*16 + 8..15] = lo chunks
__global__ __launch_bounds__(256) void knrm_prep_kernel(
    const float* __restrict__ emb, uint4* __restrict__ wse, int vocab)
{
    const int tid = threadIdx.x;
    const int row = blockIdx.x * 32 + (tid >> 3);
    const int cb  = tid & 7;
    if (row >= vocab) return;   // whole 8-lane group exits together

    const float* src = emb + (size_t)row * 50;
    float v[8];
    float ss = 0.f;
    #pragma unroll
    for (int p = 0; p < 4; ++p) {
        int e = cb * 8 + 2 * p;
        float2 t;
        if (e + 2 <= 50) t = *(const float2*)(src + e);
        else             t = make_float2(0.f, 0.f);
        v[2*p]   = t.x;
        v[2*p+1] = t.y;
        ss = fmaf(t.x, t.x, fmaf(t.y, t.y, ss));
    }
    ss += __shfl_xor(ss, 1, 64);
    ss += __shfl_xor(ss, 2, 64);
    ss += __shfl_xor(ss, 4, 64);
    float rn = __builtin_amdgcn_rsqf(ss);

    unsigned hw[4], lw[4];
    #pragma unroll
    for (int p = 0; p < 4; ++p) {
        float a = v[2*p]   * rn;
        float b = v[2*p+1] * rn;
        unsigned ha = __float_as_uint(a) & 0xFFFF0000u;
        unsigned hb = __float_as_uint(b) & 0xFFFF0000u;
        float la = a - __uint_as_float(ha);
        float lb = b - __uint_as_float(hb);
        hw[p] = (ha >> 16) | hb;
        lw[p] = (__float_as_uint(la) >> 16) | (__float_as_uint(lb) & 0xFFFF0000u);
    }
    wse[(size_t)row * 16 + cb]     = make_uint4(hw[0], hw[1], hw[2], hw[3]);
    wse[(size_t)row * 16 + 8 + cb] = make_uint4(lw[0], lw[1], lw[2], lw[3]);
}

__device__ __forceinline__ short8 frag_ld(const uint4* mat, int row, int chunk)
{
    return __builtin_bit_cast(short8, mat[row * 8 + (chunk ^ (row & 7))]);
}

// One block = one (batch, pass). 256 threads = 4 waves.
template<bool PRE>
__global__ __launch_bounds__(256, 4) void knrm_pass_kernel(
    const int* __restrict__ q1, const int* __restrict__ d1,
    const int* __restrict__ q2, const int* __restrict__ d2,
    const float* __restrict__ emb, const uint4* __restrict__ wse,
    const float* __restrict__ mlp_w, float* __restrict__ ws_logit)
{
    __shared__ uint4 qh4[32 * 8], ql4[32 * 8];   // 32 rows x 64 bf16 (hi/lo)
    __shared__ uint4 dh4[32 * 8], dl4[32 * 8];
    __shared__ float Swk[4][21][16];
    __shared__ float wred[4];

    const int tid  = threadIdx.x;
    const int bx   = blockIdx.x;
    const int b    = bx >> 1;
    const int lane = tid & 63;
    const int wave = tid >> 6;
    const int g    = lane >> 4;          // k-group 0..3

    const int* qidx = ((bx & 1) ? q2 : q1) + b * 32;
    const int* didx = ((bx & 1) ? d2 : d1) + b * 512;

    const int srow = tid >> 3;           // staging row 0..31
    const int scb  = tid & 7;            // staging chunk 0..7
    const int spos = srow * 8 + (scb ^ (srow & 7));

    // ---- stage Q (once) ----
    if constexpr (PRE) {
        const uint4* s4 = wse + (size_t)qidx[srow] * 16 + scb;
        qh4[spos] = s4[0];
        ql4[spos] = s4[8];
    } else {
        stage_row_chunk(emb, qidx[srow], srow, scb, qh4, ql4);
    }
    __syncthreads();

    // ---- B-operand fragments (fixed for the whole pass) ----
    const int qrow = (wave >> 1) * 16 + (lane & 15);
    short8 Bh0 = frag_ld(qh4, qrow, g);
    short8 Bh1 = frag_ld(qh4, qrow, 4 + g);
    short8 Bl0 = frag_ld(ql4, qrow, g);
    short8 Bl1 = frag_ld(ql4, qrow, 4 + g);

    f32x2 acc2[21];
    #pragma unroll
    for (int k = 0; k < 21; ++k) acc2[k] = (f32x2){0.f, 0.f};

    const int dt = wave & 1;

    for (int c = 0; c < 16; ++c) {
        __syncthreads();   // previous chunk fully consumed
        if constexpr (PRE) {
            const uint4* s4 = wse + (size_t)didx[c * 32 + srow] * 16 + scb;
            dh4[spos] = s4[0];
            dl4[spos] = s4[8];
        } else {
            stage_row_chunk(emb, didx[c * 32 + srow], srow, scb, dh4, dl4);
        }
        __syncthreads();

        int arow = dt * 16 + (lane & 15);
        short8 Ah0 = frag_ld(dh4, arow, g);
        short8 Ah1 = frag_ld(dh4, arow, 4 + g);
        short8 Al0 = frag_ld(dl4, arow, g);
        short8 Al1 = frag_ld(dl4, arow, 4 + g);

        f32x4 C = {0.f, 0.f, 0.f, 0.f};
        C = __builtin_amdgcn_mfma_f32_16x16x32_bf16(Ah0, Bh0, C, 0, 0, 0);
        C = __builtin_amdgcn_mfma_f32_16x16x32_bf16(Ah1, Bh1, C, 0, 0, 0);
        C = __builtin_amdgcn_mfma_f32_16x16x32_bf16(Ah0, Bl0, C, 0, 0, 0);
        C = __builtin_amdgcn_mfma_f32_16x16x32_bf16(Ah1, Bl1, C, 0, 0, 0);
        C = __builtin_amdgcn_mfma_f32_16x16x32_bf16(Al0, Bh0, C, 0, 0, 0);
        C = __builtin_amdgcn_mfma_f32_16x16x32_bf16(Al1, Bh1, C, 0, 0, 0);

        f32x2 a01 = {C[0], C[1]};
        f32x2 a23 = {C[2], C[3]};
        kern21(a01, acc2);
        kern21(a23, acc2);
    }

    // ---- fold packed pair, then the 4 doc-row groups ----
    float acc[21];
    #pragma unroll
    for (int k = 0; k < 21; ++k) {
        float v = acc2[k].x + acc2[k].y;
        v += __shfl_xor(v, 16, 64);
        v += __shfl_xor(v, 32, 64);
        acc[k] = v;
    }
    if (lane < 16) {
        #pragma unroll
        for (int k = 0; k < 21; ++k) Swk[wave][k][lane] = acc[k];
    }
    __syncthreads();

    // ---- log1p + kernel weights + block reduction ----
    float local = 0.f;
    for (int p = tid; p < 21 * 32; p += 256) {
        int k = p >> 5, q = p & 31;
        int wp = (q >> 4) * 2;     // waves {0,1} -> q 0..15, {2,3} -> q 16..31
        float S = Swk[wp][k][q & 15] + Swk[wp + 1][k][q & 15];
        local += mlp_w[k] * log1pf(S);
    }
    #pragma unroll
    for (int off = 1; off < 64; off <<= 1) local += __shfl_xor(local, off, 64);
    if (lane == 0) wred[wave] = local;
    __syncthreads();
    if (tid == 0)
        ws_logit[bx] = wred[0] + wred[1] + wred[2] + wred[3];  // bias cancels in l1-l2
}

__global__ void knrm_final_kernel(const float* __restrict__ ws_logit,
                                  float* __restrict__ out, int B)
{
    int i = blockIdx.x * 256 + threadIdx.x;
    if (i < B) {
        float x = ws_logit[2 * i] - ws_logit[2 * i + 1];
        out[i] = 1.0f / (1.0f + fexp2(-LOG2E * x));
    }
}

extern "C" void kernel_launch(void* const* d_in, const int* in_sizes, int n_in,
                              void* d_out, int out_size, void* d_ws, size_t ws_size,
                              hipStream_t stream) {
    const int*   q1    = (const int*)d_in[0];
    const int*   d1    = (const int*)d_in[1];
    const int*   q2    = (const int*)d_in[2];
    const int*   d2    = (const int*)d_in[3];
    const float* emb   = (const float*)d_in[4];
    const float* mlp_w = (const float*)d_in[5];
    float*       out   = (float*)d_out;

    const int B     = out_size;            // 1024
    const int vocab = in_sizes[4] / 50;    // 100000

    float* ws_logit = (float*)d_ws;                       // 2*B floats = 8192 B
    uint4* wse      = (uint4*)((char*)d_ws + 8192);       // prepped embeddings
    size_t need     = 8192 + (size_t)vocab * 256;

    if (ws_size >= need) {
        knrm_prep_kernel<<<dim3((vocab + 31) / 32), dim3(256), 0, stream>>>(emb, wse, vocab);
        knrm_pass_kernel<true><<<dim3(2 * B), dim3(256), 0, stream>>>(
            q1, d1, q2, d2, emb, wse, mlp_w, ws_logit);
    } else {
        knrm_pass_kernel<false><<<dim3(2 * B), dim3(256), 0, stream>>>(
            q1, d1, q2, d2, emb, (const uint4*)nullptr, mlp_w, ws_logit);
    }
    knrm_final_kernel<<<dim3((B + 255) / 256), dim3(256), 0, stream>>>(ws_logit, out, B);
}

// Round 5
// 79.452 us; speedup vs baseline: 3.9277x; 1.0289x over previous
//
#include <hip/hip_runtime.h>
#include <math.h>

#define LOG2E 1.4426950408889634f
#define E1 0.36787944117144233f

typedef __attribute__((ext_vector_type(8))) short short8;   // 8 bf16 (4 VGPR)
typedef __attribute__((ext_vector_type(4))) float f32x4;    // MFMA C/D
typedef __attribute__((ext_vector_type(2))) float f32x2;    // packed-f32 pair

__device__ __forceinline__ float fexp2(float x) { return __builtin_amdgcn_exp2f(x); }

// 21 Gaussian kernels for 2 sims, accumulated into acc[21] (f32x2).
// g_k = exp(-50(s-mu_k)^2), mu_k=(2k-19)/20; ratio(k->k+1) = r*e^{9-k}, r=e^{10s}.
// Chain rooted at center k=9 so all intermediates <= 1 (validated R1/R2/R4).
__device__ __forceinline__ void kern21(f32x2 s, f32x2* acc)
{
    // clamp: 1 med3 per component (NaN insurance; in-range sims unaffected)
    s.x = __builtin_amdgcn_fmed3f(s.x, -1.1f, 1.1f);
    s.y = __builtin_amdgcn_fmed3f(s.y, -1.1f, 1.1f);

    f32x2 m = s * 14.426950408889634f;               // 10*log2(e)*s
    f32x2 r, ri, gc;
    r.x  = fexp2(m.x);   r.y  = fexp2(m.y);          // e^{10 s}
    ri.x = fexp2(-m.x);  ri.y = fexp2(-m.y);         // e^{-10 s}
    f32x2 t9 = s + 0.05f;                            // center mu_9 = -0.05
    f32x2 ga = (t9 * t9) * -72.13475204444817f;      // -50/ln2
    gc.x = fexp2(ga.x);  gc.y = fexp2(ga.y);         // g_9

    acc[9] += gc;
    f32x2 t = r;
    f32x2 g = gc * t;
    acc[10] += g;
    #pragma unroll
    for (int k = 11; k <= 19; ++k) { t *= E1; g *= t; acc[k] += g; }
    t = ri * E1;
    g = gc * t;
    acc[8] += g;
    #pragma unroll
    for (int k = 7; k >= 0; --k) { t *= E1; g *= t; acc[k] += g; }
    // exact kernel (mu=1, sigma=0.001): nonzero only for |s-1| <~ 0.005 ->
    // wave-uniform skip, taken ~0.1% of the time on random vocab.
    if (__any(fmaxf(s.x, s.y) > 0.995f)) {
        f32x2 te = s - 1.0f;
        f32x2 ea = (te * te) * -721347.5204444817f;
        f32x2 ge; ge.x = fexp2(ea.x); ge.y = fexp2(ea.y);
        acc[20] += ge;
    }
}

// ---- fallback in-kernel staging (R2-proven path, used when ws too small) ----
__device__ __forceinline__ void stage_row_chunk(
    const float* __restrict__ emb, int tok, int row, int cb,
    uint4* __restrict__ hmat, uint4* __restrict__ lmat)
{
    const float* src = emb + (size_t)tok * 50;
    float v[8];
    float ss = 0.f;
    #pragma unroll
    for (int p = 0; p < 4; ++p) {
        int e = cb * 8 + 2 * p;
        float2 t;
        if (e + 2 <= 50) t = *(const float2*)(src + e);
        else             t = make_float2(0.f, 0.f);
        v[2*p]   = t.x;
        v[2*p+1] = t.y;
        ss = fmaf(t.x, t.x, fmaf(t.y, t.y, ss));
    }
    ss += __shfl_xor(ss, 1, 64);
    ss += __shfl_xor(ss, 2, 64);
    ss += __shfl_xor(ss, 4, 64);
    float rn = __builtin_amdgcn_rsqf(ss);

    unsigned hw[4], lw[4];
    #pragma unroll
    for (int p = 0; p < 4; ++p) {
        float a = v[2*p]   * rn;
        float b = v[2*p+1] * rn;
        unsigned ha = __float_as_uint(a) & 0xFFFF0000u;
        unsigned hb = __float_as_uint(b) & 0xFFFF0000u;
        float la = a - __uint_as_float(ha);
        float lb = b - __uint_as_float(hb);
        hw[p] = (ha >> 16) | hb;
        lw[p] = (__float_as_uint(la) >> 16) | (__float_as_uint(lb) & 0xFFFF0000u);
    }
    int cidx = cb ^ (row & 7);
    hmat[row * 8 + cidx] = make_uint4(hw[0], hw[1], hw[2], hw[3]);
    lmat[row * 8 + cidx] = make_uint4(lw[0], lw[1], lw[2], lw[3]);
}

// ---- prep: normalize + bf16 hi/lo split every vocab row into ws ----
// layout: wse[tok*16 + 0..7] = hi chunks, wse[tok*16 + 8..15] = lo chunks
__global__ __launch_bounds__(256) void knrm_prep_kernel(
    const float* __restrict__ emb, uint4* __restrict__ wse, int vocab)
{
    const int tid = threadIdx.x;
    const int row = blockIdx.x * 32 + (tid >> 3);
    const int cb  = tid & 7;
    if (row >= vocab) return;   // whole 8-lane group exits together

    const float* src = emb + (size_t)row * 50;
    float v[8];
    float ss = 0.f;
    #pragma unroll
    for (int p = 0; p < 4; ++p) {
        int e = cb * 8 + 2 * p;
        float2 t;
        if (e + 2 <= 50) t = *(const float2*)(src + e);
        else             t = make_float2(0.f, 0.f);
        v[2*p]   = t.x;
        v[2*p+1] = t.y;
        ss = fmaf(t.x, t.x, fmaf(t.y, t.y, ss));
    }
    ss += __shfl_xor(ss, 1, 64);
    ss += __shfl_xor(ss, 2, 64);
    ss += __shfl_xor(ss, 4, 64);
    float rn = __builtin_amdgcn_rsqf(ss);

    unsigned hw[4], lw[4];
    #pragma unroll
    for (int p = 0; p < 4; ++p) {
        float a = v[2*p]   * rn;
        float b = v[2*p+1] * rn;
        unsigned ha = __float_as_uint(a) & 0xFFFF0000u;
        unsigned hb = __float_as_uint(b) & 0xFFFF0000u;
        float la = a - __uint_as_float(ha);
        float lb = b - __uint_as_float(hb);
        hw[p] = (ha >> 16) | hb;
        lw[p] = (__float_as_uint(la) >> 16) | (__float_as_uint(lb) & 0xFFFF0000u);
    }
    wse[(size_t)row * 16 + cb]     = make_uint4(hw[0], hw[1], hw[2], hw[3]);
    wse[(size_t)row * 16 + 8 + cb] = make_uint4(lw[0], lw[1], lw[2], lw[3]);
}

__device__ __forceinline__ short8 frag_ld(const uint4* mat, int row, int chunk)
{
    return __builtin_bit_cast(short8, mat[row * 8 + (chunk ^ (row & 7))]);
}

// One block = one (batch, pass). 256 threads = 4 waves.
// PRE path: software-pipelined — double-buffered doc LDS, depth-1 gather
// prefetch, depth-2 token-index prefetch, ONE barrier per chunk (buffer
// parity replaces the second barrier: chunk c reads buf[c&1], writes
// buf[(c+1)&1], and the end-of-chunk barrier orders write(c)->read(c+1)).
template<bool PRE>
__global__ __launch_bounds__(256, 4) void knrm_pass_kernel(
    const int* __restrict__ q1, const int* __restrict__ d1,
    const int* __restrict__ q2, const int* __restrict__ d2,
    const float* __restrict__ emb, const uint4* __restrict__ wse,
    const float* __restrict__ mlp_w, float* __restrict__ ws_logit)
{
    __shared__ uint4 qh4[32 * 8], ql4[32 * 8];        // 32 rows x 64 bf16 hi/lo
    __shared__ uint4 dh4[2][32 * 8], dl4[2][32 * 8];  // double-buffered docs
    __shared__ float Swk[4][21][16];
    __shared__ float wred[4];

    const int tid  = threadIdx.x;
    const int bx   = blockIdx.x;
    const int b    = bx >> 1;
    const int lane = tid & 63;
    const int wave = tid >> 6;
    const int g    = lane >> 4;          // k-group 0..3

    const int* qidx = ((bx & 1) ? q2 : q1) + b * 32;
    const int* didx = ((bx & 1) ? d2 : d1) + b * 512;

    const int srow = tid >> 3;           // staging row 0..31
    const int scb  = tid & 7;            // staging chunk 0..7
    const int spos = srow * 8 + (scb ^ (srow & 7));

    int tokN = 0;
    if constexpr (PRE) {
        // stage Q + doc chunk 0; prefetch chunk-1 token index
        const uint4* sq = wse + (size_t)qidx[srow] * 16 + scb;
        qh4[spos] = sq[0];
        ql4[spos] = sq[8];
        const uint4* s0 = wse + (size_t)didx[srow] * 16 + scb;
        dh4[0][spos] = s0[0];
        dl4[0][spos] = s0[8];
        tokN = didx[32 + srow];
    } else {
        stage_row_chunk(emb, qidx[srow], srow, scb, qh4, ql4);
    }
    __syncthreads();

    // ---- B-operand fragments (fixed for the whole pass) ----
    const int qrow = (wave >> 1) * 16 + (lane & 15);
    short8 Bh0 = frag_ld(qh4, qrow, g);
    short8 Bh1 = frag_ld(qh4, qrow, 4 + g);
    short8 Bl0 = frag_ld(ql4, qrow, g);
    short8 Bl1 = frag_ld(ql4, qrow, 4 + g);

    f32x2 acc2[21];
    #pragma unroll
    for (int k = 0; k < 21; ++k) acc2[k] = (f32x2){0.f, 0.f};

    const int dt   = wave & 1;
    const int arow = dt * 16 + (lane & 15);

    if constexpr (PRE) {
        for (int c = 0; c < 16; ++c) {
            // 1) issue next chunk's gather FIRST (idx already in hand)
            uint4 ph, pl;
            if (c < 15) {
                const uint4* sn = wse + (size_t)tokN * 16 + scb;
                ph = sn[0];
                pl = sn[8];
            }
            // 2) prefetch token index two chunks ahead
            if (c < 14) tokN = didx[(c + 2) * 32 + srow];

            // 3) compute current chunk from buf[c&1]
            const uint4* dhb = dh4[c & 1];
            const uint4* dlb = dl4[c & 1];
            short8 Ah0 = frag_ld(dhb, arow, g);
            short8 Ah1 = frag_ld(dhb, arow, 4 + g);
            short8 Al0 = frag_ld(dlb, arow, g);
            short8 Al1 = frag_ld(dlb, arow, 4 + g);

            f32x4 C = {0.f, 0.f, 0.f, 0.f};
            C = __builtin_amdgcn_mfma_f32_16x16x32_bf16(Ah0, Bh0, C, 0, 0, 0);
            C = __builtin_amdgcn_mfma_f32_16x16x32_bf16(Ah1, Bh1, C, 0, 0, 0);
            C = __builtin_amdgcn_mfma_f32_16x16x32_bf16(Ah0, Bl0, C, 0, 0, 0);
            C = __builtin_amdgcn_mfma_f32_16x16x32_bf16(Ah1, Bl1, C, 0, 0, 0);
            C = __builtin_amdgcn_mfma_f32_16x16x32_bf16(Al0, Bh0, C, 0, 0, 0);
            C = __builtin_amdgcn_mfma_f32_16x16x32_bf16(Al1, Bh1, C, 0, 0, 0);

            f32x2 a01 = {C[0], C[1]};
            f32x2 a23 = {C[2], C[3]};
            kern21(a01, acc2);
            kern21(a23, acc2);

            // 4) land the prefetched gather into the other buffer
            if (c < 15) {
                dh4[(c + 1) & 1][spos] = ph;   // compiler inserts vmcnt wait
                dl4[(c + 1) & 1][spos] = pl;
            }
            __syncthreads();
        }
    } else {
        for (int c = 0; c < 16; ++c) {
            if (c) __syncthreads();
            stage_row_chunk(emb, didx[c * 32 + srow], srow, scb, dh4[0], dl4[0]);
            __syncthreads();

            short8 Ah0 = frag_ld(dh4[0], arow, g);
            short8 Ah1 = frag_ld(dh4[0], arow, 4 + g);
            short8 Al0 = frag_ld(dl4[0], arow, g);
            short8 Al1 = frag_ld(dl4[0], arow, 4 + g);

            f32x4 C = {0.f, 0.f, 0.f, 0.f};
            C = __builtin_amdgcn_mfma_f32_16x16x32_bf16(Ah0, Bh0, C, 0, 0, 0);
            C = __builtin_amdgcn_mfma_f32_16x16x32_bf16(Ah1, Bh1, C, 0, 0, 0);
            C = __builtin_amdgcn_mfma_f32_16x16x32_bf16(Ah0, Bl0, C, 0, 0, 0);
            C = __builtin_amdgcn_mfma_f32_16x16x32_bf16(Ah1, Bl1, C, 0, 0, 0);
            C = __builtin_amdgcn_mfma_f32_16x16x32_bf16(Al0, Bh0, C, 0, 0, 0);
            C = __builtin_amdgcn_mfma_f32_16x16x32_bf16(Al1, Bh1, C, 0, 0, 0);

            f32x2 a01 = {C[0], C[1]};
            f32x2 a23 = {C[2], C[3]};
            kern21(a01, acc2);
            kern21(a23, acc2);
        }
        __syncthreads();
    }

    // ---- fold packed pair, then the 4 doc-row groups ----
    float acc[21];
    #pragma unroll
    for (int k = 0; k < 21; ++k) {
        float v = acc2[k].x + acc2[k].y;
        v += __shfl_xor(v, 16, 64);
        v += __shfl_xor(v, 32, 64);
        acc[k] = v;
    }
    if (lane < 16) {
        #pragma unroll
        for (int k = 0; k < 21; ++k) Swk[wave][k][lane] = acc[k];
    }
    __syncthreads();

    // ---- log1p + kernel weights + block reduction ----
    float local = 0.f;
    for (int p = tid; p < 21 * 32; p += 256) {
        int k = p >> 5, q = p & 31;
        int wp = (q >> 4) * 2;     // waves {0,1} -> q 0..15, {2,3} -> q 16..31
        float S = Swk[wp][k][q & 15] + Swk[wp + 1][k][q & 15];
        local += mlp_w[k] * log1pf(S);
    }
    #pragma unroll
    for (int off = 1; off < 64; off <<= 1) local += __shfl_xor(local, off, 64);
    if (lane == 0) wred[wave] = local;
    __syncthreads();
    if (tid == 0)
        ws_logit[bx] = wred[0] + wred[1] + wred[2] + wred[3];  // bias cancels in l1-l2
}

__global__ void knrm_final_kernel(const float* __restrict__ ws_logit,
                                  float* __restrict__ out, int B)
{
    int i = blockIdx.x * 256 + threadIdx.x;
    if (i < B) {
        float x = ws_logit[2 * i] - ws_logit[2 * i + 1];
        out[i] = 1.0f / (1.0f + fexp2(-LOG2E * x));
    }
}

extern "C" void kernel_launch(void* const* d_in, const int* in_sizes, int n_in,
                              void* d_out, int out_size, void* d_ws, size_t ws_size,
                              hipStream_t stream) {
    const int*   q1    = (const int*)d_in[0];
    const int*   d1    = (const int*)d_in[1];
    const int*   q2    = (const int*)d_in[2];
    const int*   d2    = (const int*)d_in[3];
    const float* emb   = (const float*)d_in[4];
    const float* mlp_w = (const float*)d_in[5];
    float*       out   = (float*)d_out;

    const int B     = out_size;            // 1024
    const int vocab = in_sizes[4] / 50;    // 100000

    float* ws_logit = (float*)d_ws;                       // 2*B floats = 8192 B
    uint4* wse      = (uint4*)((char*)d_ws + 8192);       // prepped embeddings
    size_t need     = 8192 + (size_t)vocab * 256;

    if (ws_size >= need) {
        knrm_prep_kernel<<<dim3((vocab + 31) / 32), dim3(256), 0, stream>>>(emb, wse, vocab);
        knrm_pass_kernel<true><<<dim3(2 * B), dim3(256), 0, stream>>>(
            q1, d1, q2, d2, emb, wse, mlp_w, ws_logit);
    } else {
        knrm_pass_kernel<false><<<dim3(2 * B), dim3(256), 0, stream>>>(
            q1, d1, q2, d2, emb, (const uint4*)nullptr, mlp_w, ws_logit);
    }
    knrm_final_kernel<<<dim3((B + 255) / 256), dim3(256), 0, stream>>>(ws_logit, out, B);
}